// Round 9
// baseline (286.701 us; speedup 1.0000x reference)
//
#include <hip/hip_runtime.h>
#include <hip/hip_bf16.h>

// DFAChebNet forward.
//  layer: x@W0 + (agg(x)-x)@W1 + b == x@(W0-W1) + agg(x@W1) + b   (project first)
//  aggregation: CSR pull-gather; CSR built by LDS-staged counting sort.
//  R9: (a) hist+scan front-end replaced by atomic bucket reservation into a
//  CAP-slotted staging buffer (one atomicAdd per bucket per block);
//  (b) proj1 splits K by wave (kh = tid>>7, wave-uniform -> W stays s_load),
//  2x grid for latency hiding, partials combined via padded LDS tile.

#include <hip/hip_fp16.h>

constexpr int NN   = 100000;
constexpr int NE   = 1600000;
constexpr int FIN  = 128;
constexpr int HID  = 16;
constexpr int NCLS = 32;

constexpr int RB    = 256;                         // rows per bucket
constexpr int NBKT  = (NN + RB - 1) / RB;          // 391
constexpr int EPB   = 4096;                        // edges per partition block
constexpr int EPT   = EPB / 256;                   // 16 edges per thread
constexpr int GP    = (NE + EPB - 1) / EPB;        // 391
constexpr int CAP   = 8192;                        // bucket slot capacity (mean 4096)

typedef float f32x2 __attribute__((ext_vector_type(2)));

#if defined(__has_builtin)
#if __has_builtin(__builtin_amdgcn_cvt_pk_f32_fp8)
#define HAVE_CVT_FP8 1
#endif
#endif

// fp8 e4m3fn encode (RNE, subnormals flushed to 0, clamp at 448)
static __device__ __forceinline__ unsigned int f2e4m3(float f) {
    union { float f; unsigned int u; } v; v.f = f;
    unsigned int s = (v.u >> 24) & 0x80u;
    unsigned int au = v.u & 0x7fffffffu;
    if (au > 0x43E00000u) au = 0x43E00000u;        // clamp to 448
    au += 0x7ffffu + ((au >> 20) & 1u);            // RNE into 3-bit mantissa
    int e4 = (int)(au >> 23) - 120;                // 127-7
    unsigned int m = (au >> 20) & 7u;
    unsigned int byte = (e4 <= 0) ? 0u : (((unsigned int)e4 << 3) | m);
    return s | byte;
}
// 4 packed fp8 -> acc[0..3] += w * val
static __device__ __forceinline__ void fp8x4_fma(unsigned int v, float w, float* acc) {
#ifdef HAVE_CVT_FP8
    f32x2 lo = __builtin_amdgcn_cvt_pk_f32_fp8((int)v, false);
    f32x2 hi = __builtin_amdgcn_cvt_pk_f32_fp8((int)v, true);
    acc[0] += w * lo.x; acc[1] += w * lo.y;
    acc[2] += w * hi.x; acc[3] += w * hi.y;
#else
#pragma unroll
    for (int i = 0; i < 4; i++) {
        unsigned int b = (v >> (8 * i)) & 0xffu;
        float f = __int_as_float((int)(((b & 0x80u) << 24) | ((b & 0x7fu) << 20))) * 0x1p120f;
        acc[i] += w * f;
    }
#endif
}
// edge record: col(17 bits) | w(15 bits = signless bf16, RNE)
static __device__ __forceinline__ unsigned int wpack(float wf) {
    unsigned int b = __float_as_uint(wf) + 0x8000u;
    return (b >> 16) & 0x7fffu;
}
static __device__ __forceinline__ float wdec(unsigned int u) {
    return __uint_as_float((u >> 17) << 16);
}

// ---- zero the bucket cursors ----
__global__ void k_zero_cur(int* __restrict__ bucketCursor) {
    int i = blockIdx.x * blockDim.x + threadIdx.x;
    if (i < NBKT) bucketCursor[i] = 0;
}

// ---- pass B: LDS-staged partition; atomic reservation into slotted buffer ----
__global__ __launch_bounds__(256) void k_partition(
    const int* __restrict__ row, const int* __restrict__ col,
    const float* __restrict__ w, int* __restrict__ bucketCursor,
    int2* __restrict__ partS) {
    __shared__ int2 stage[EPB];              // 32KB
    __shared__ unsigned short sbkt[EPB];     // 8KB
    __shared__ int cnt[NBKT];
    __shared__ int lofs[NBKT];
    __shared__ int cursor[NBKT];
    __shared__ int gbase[NBKT];
    __shared__ int sa[512], sb[512];
    int tid = threadIdx.x;
    long ebase = (long)blockIdx.x * EPB;
    int rr[EPT]; int cc[EPT]; float wv[EPT];
#pragma unroll
    for (int i = 0; i < EPT; i++) {
        long e = ebase + i * 256 + tid;
        if (e < NE) { rr[i] = row[e]; cc[i] = col[e]; wv[i] = w[e]; }
        else rr[i] = -1;
    }
    for (int i = tid; i < NBKT; i += 256) cnt[i] = 0;
    __syncthreads();
#pragma unroll
    for (int i = 0; i < EPT; i++)
        if (rr[i] >= 0) atomicAdd(&cnt[rr[i] >> 8], 1);
    __syncthreads();
    for (int i = tid; i < 512; i += 256) sa[i] = (i < NBKT) ? cnt[i] : 0;
    __syncthreads();
    int* src = sa; int* dst = sb;
    for (int off = 1; off < 512; off <<= 1) {
        for (int i = tid; i < 512; i += 256)
            dst[i] = src[i] + ((i >= off) ? src[i - off] : 0);
        __syncthreads();
        int* t = src; src = dst; dst = t;
    }
    for (int i = tid; i < NBKT; i += 256) {
        int ex = src[i] - cnt[i];
        lofs[i] = ex;
        cursor[i] = ex;
        int go = (cnt[i] > 0) ? atomicAdd(&bucketCursor[i], cnt[i]) : 0;
        gbase[i] = i * CAP + go;
    }
    __syncthreads();
#pragma unroll
    for (int i = 0; i < EPT; i++) {
        if (rr[i] >= 0) {
            int b = rr[i] >> 8;
            int p = atomicAdd(&cursor[b], 1);
            int2 v;
            v.x = cc[i] | ((rr[i] & 255) << 17);
            v.y = __float_as_int(wv[i]);
            stage[p] = v;
            sbkt[p] = (unsigned short)b;
        }
    }
    __syncthreads();
    int total = (int)min((long)EPB, NE - ebase);
    for (int i = tid; i < total; i += 256) {
        int b = sbkt[i];
        partS[gbase[b] + (i - lofs[b])] = stage[i];
    }
}

// ---- exclusive scan of the 391 bucket totals (one wave) ----
__global__ void k_scan_buckets(const int* __restrict__ bucketCursor,
                               int* __restrict__ bucketStart) {
    int lane = threadIdx.x;  // 64 threads
    int v[8], e[8];
    int s = 0;
#pragma unroll
    for (int t = 0; t < 8; t++) {
        int idx = lane * 8 + t;
        v[t] = (idx < NBKT) ? bucketCursor[idx] : 0;
        e[t] = s;
        s += v[t];
    }
    int sc = s;
    for (int off = 1; off < 64; off <<= 1) {
        int up = __shfl_up(sc, off, 64);
        if (lane >= off) sc += up;
    }
    int excl = sc - s;
#pragma unroll
    for (int t = 0; t < 8; t++) {
        int idx = lane * 8 + t;
        if (idx < NBKT) bucketStart[idx] = excl + e[t];
    }
}

// ---- pass C: per-bucket sort by row; emits packed 4B CSR, rowptr, dinv ----
__global__ __launch_bounds__(256) void k_bucket_sort(
    const int2* __restrict__ partS, const int* __restrict__ bucketCursor,
    const int* __restrict__ bucketStart,
    unsigned int* __restrict__ partC, int* __restrict__ rowptr,
    float* __restrict__ dinv) {
    __shared__ int2 stage[CAP];          // 64KB
    __shared__ int hist[RB];
    __shared__ int cursor[RB];
    __shared__ int wtot[4];
    int b = blockIdx.x;
    int tid = threadIdx.x;
    int start = bucketStart[b];
    int count = bucketCursor[b];
    const int2* src = partS + (long)b * CAP;
    hist[tid] = 0;
    __syncthreads();
    for (int i = tid; i < count; i += 256)
        atomicAdd(&hist[(src[i].x >> 17) & 255], 1);
    __syncthreads();
    int lane = tid & 63, wv = tid >> 6;
    int v = hist[tid];
    int sc = v;
#pragma unroll
    for (int off = 1; off < 64; off <<= 1) {
        int up = __shfl_up(sc, off, 64);
        if (lane >= off) sc += up;
    }
    if (lane == 63) wtot[wv] = sc;
    __syncthreads();
    int add = 0;
    for (int w2 = 0; w2 < wv; w2++) add += wtot[w2];
    int ex = sc + add - v;
    int node = b * RB + tid;
    if (node <= NN) rowptr[node] = start + ex;   // node==NN -> NE (last bucket)
    cursor[tid] = ex;
    __syncthreads();
    for (int i = tid; i < count; i += 256) {
        int2 p = src[i];
        int rl = (p.x >> 17) & 255;
        int pos = atomicAdd(&cursor[rl], 1);
        int2 c; c.x = p.x & 0x1FFFF; c.y = p.y;
        if (pos < CAP) stage[pos] = c;
    }
    __syncthreads();
    {
        int rend = cursor[tid];
        float d = 0.f;
        for (int i = ex; i < rend; i++) d += __int_as_float(stage[i].y);
        if (node < NN) dinv[node] = d > 0.f ? rsqrtf(d) : 0.f;
    }
    for (int i = tid; i < count; i += 256)
        if (i < CAP) {
            int2 p = stage[i];
            partC[start + i] = (unsigned int)p.x | (wpack(__int_as_float(p.y)) << 17);
        }
}

// xa = x@(W1_0-W1_1)+b1 (fp32) ; xb' = dinv[n] * (x@W1_1) (fp8 e4m3).
// Block = 128 nodes x 2 k-halves (kh = tid>>7, wave-uniform -> W via s_load).
// Partials combined through +33-padded LDS tile.
__global__ __launch_bounds__(256) void k_proj1(
    const float* __restrict__ x, const float* __restrict__ W0,
    const float* __restrict__ W1, const float* __restrict__ b1,
    const float* __restrict__ dinv,
    float* __restrict__ xa, unsigned char* __restrict__ xb8) {
    __shared__ float red[128 * 33];          // 16.9KB, conflict-free
    int tid = threadIdx.x;
    int nl = tid & 127;
    int kh = tid >> 7;                       // wave-uniform
    long n = (long)blockIdx.x * 128 + nl;
    bool valid = n < NN;
    long nc = valid ? n : 0;
    const float4* xg = (const float4*)x + nc * 32 + kh * 16;
    float accA[HID], accB[HID];
#pragma unroll
    for (int o = 0; o < HID; o++) { accA[o] = 0.f; accB[o] = 0.f; }
    float4 bufA[8], bufB[8];
#pragma unroll
    for (int m = 0; m < 8; m++) bufA[m] = xg[m];
#pragma unroll
    for (int m = 0; m < 8; m++) bufB[m] = xg[8 + m];

#define PROJ1_CHUNK(BUF, C)                                            \
    {                                                                   \
        const float* W0p = W0 + (C) * 32 * HID;                         \
        const float* W1p = W1 + (C) * 32 * HID;                         \
        _Pragma("unroll")                                               \
        for (int m = 0; m < 8; m++) {                                   \
            float xv[4] = {BUF[m].x, BUF[m].y, BUF[m].z, BUF[m].w};     \
            _Pragma("unroll")                                           \
            for (int q = 0; q < 4; q++) {                               \
                int k = m * 4 + q;                                      \
                _Pragma("unroll")                                       \
                for (int o = 0; o < HID; o++) accA[o] += xv[q] * W0p[k * HID + o]; \
                _Pragma("unroll")                                       \
                for (int o = 0; o < HID; o++) accB[o] += xv[q] * W1p[k * HID + o]; \
            }                                                           \
        }                                                               \
    }

    PROJ1_CHUNK(bufA, kh * 2 + 0)
    PROJ1_CHUNK(bufB, kh * 2 + 1)
#undef PROJ1_CHUNK

    if (kh == 1) {
#pragma unroll
        for (int o = 0; o < HID; o++) red[nl * 33 + o] = accA[o];
#pragma unroll
        for (int o = 0; o < HID; o++) red[nl * 33 + HID + o] = accB[o];
    }
    __syncthreads();
    if (kh == 1 || !valid) return;
#pragma unroll
    for (int o = 0; o < HID; o++) accA[o] += red[nl * 33 + o];
#pragma unroll
    for (int o = 0; o < HID; o++) accB[o] += red[nl * 33 + HID + o];

    float4* xap = (float4*)(xa + n * HID);
#pragma unroll
    for (int q = 0; q < 4; q++) {
        float4 va;
        va.x = accA[4*q+0] - accB[4*q+0] + b1[4*q+0];
        va.y = accA[4*q+1] - accB[4*q+1] + b1[4*q+1];
        va.z = accA[4*q+2] - accB[4*q+2] + b1[4*q+2];
        va.w = accA[4*q+3] - accB[4*q+3] + b1[4*q+3];
        xap[q] = va;
    }
    float dn = dinv[n];
    unsigned int pk[4];
#pragma unroll
    for (int q = 0; q < 4; q++)
        pk[q] = f2e4m3(dn * accB[4*q+0]) | (f2e4m3(dn * accB[4*q+1]) << 8)
              | (f2e4m3(dn * accB[4*q+2]) << 16) | (f2e4m3(dn * accB[4*q+3]) << 24);
    *(uint4*)(xb8 + n * HID) = make_uint4(pk[0], pk[1], pk[2], pk[3]);
}

// agg1[n,:] = dinv[n] * sum_j w_j * xb'[c_j,:].
// 1 wave = 1 node; lane = (parity p 0..15, dword d 0..3); 16 lines in flight.
__global__ __launch_bounds__(256) void k_gather1(
    const int* __restrict__ rowptr, const unsigned int* __restrict__ partC,
    const float* __restrict__ dinv, const unsigned char* __restrict__ xb8,
    float* __restrict__ agg1) {
    long t = (long)blockIdx.x * 256 + threadIdx.x;
    int n = (int)(t >> 6);
    if (n >= NN) return;
    int lane = threadIdx.x & 63;
    int d = lane & 3, p = lane >> 2;
    int s = rowptr[n], e = rowptr[n + 1];
    float acc[4] = {0.f, 0.f, 0.f, 0.f};
    for (int j = s + p; j < e; j += 16) {
        unsigned int u = partC[j];
        unsigned int v = *(const unsigned int*)(xb8 + (u & 0x1FFFF) * HID + d * 4);
        fp8x4_fma(v, wdec(u), acc);
    }
#pragma unroll
    for (int i = 0; i < 4; i++) {
        acc[i] += __shfl_xor(acc[i], 4);
        acc[i] += __shfl_xor(acc[i], 8);
        acc[i] += __shfl_xor(acc[i], 16);
        acc[i] += __shfl_xor(acc[i], 32);
    }
    if (p == 0) {
        float dn = dinv[n];
        float4 o; o.x = dn * acc[0]; o.y = dn * acc[1];
        o.z = dn * acc[2]; o.w = dn * acc[3];
        *(float4*)(agg1 + (long)n * HID + d * 4) = o;
    }
}

// h = relu(xa+agg1); ha = h@(W2_0-W2_1)+b2 (fp32) ; hb' = dinv*h@W2_1 (fp8).
__global__ __launch_bounds__(256) void k_proj2(
    const float* __restrict__ xa, const float* __restrict__ agg1,
    const float* __restrict__ W0, const float* __restrict__ W1,
    const float* __restrict__ b2, const float* __restrict__ dinv,
    float* __restrict__ ha, unsigned char* __restrict__ hb8) {
    long n = (long)blockIdx.x * 256 + threadIdx.x;
    if (n >= NN) return;
    float h[HID];
    const float4* xap = (const float4*)(xa + n * HID);
    const float4* agp = (const float4*)(agg1 + n * HID);
#pragma unroll
    for (int q = 0; q < 4; q++) {
        float4 a = xap[q], g = agp[q];
        h[4*q+0] = fmaxf(a.x + g.x, 0.f);
        h[4*q+1] = fmaxf(a.y + g.y, 0.f);
        h[4*q+2] = fmaxf(a.z + g.z, 0.f);
        h[4*q+3] = fmaxf(a.w + g.w, 0.f);
    }
    float accA[NCLS], accB[NCLS];
#pragma unroll
    for (int o = 0; o < NCLS; o++) { accA[o] = 0.f; accB[o] = 0.f; }
#pragma unroll 2
    for (int k = 0; k < HID; k++) {
        float hk = h[k];
#pragma unroll
        for (int o = 0; o < NCLS; o++) accA[o] += hk * W0[k * NCLS + o];
#pragma unroll
        for (int o = 0; o < NCLS; o++) accB[o] += hk * W1[k * NCLS + o];
    }
    float4* hap = (float4*)(ha + n * NCLS);
#pragma unroll
    for (int q = 0; q < 8; q++) {
        float4 va;
        va.x = accA[4*q+0] - accB[4*q+0] + b2[4*q+0];
        va.y = accA[4*q+1] - accB[4*q+1] + b2[4*q+1];
        va.z = accA[4*q+2] - accB[4*q+2] + b2[4*q+2];
        va.w = accA[4*q+3] - accB[4*q+3] + b2[4*q+3];
        hap[q] = va;
    }
    float dn = dinv[n];
    unsigned int pk[8];
#pragma unroll
    for (int q = 0; q < 8; q++)
        pk[q] = f2e4m3(dn * accB[4*q+0]) | (f2e4m3(dn * accB[4*q+1]) << 8)
              | (f2e4m3(dn * accB[4*q+2]) << 16) | (f2e4m3(dn * accB[4*q+3]) << 24);
    uint4* hbp = (uint4*)(hb8 + n * NCLS);
    hbp[0] = make_uint4(pk[0], pk[1], pk[2], pk[3]);
    hbp[1] = make_uint4(pk[4], pk[5], pk[6], pk[7]);
}

// out[n,:] = log_softmax(ha[n,:] + dinv[n]*sum_j w_j*hb'[c_j,:]).
// 1 wave = 1 node; lane = (parity p 0..7, dword d 0..7); unroll 2.
__global__ __launch_bounds__(256) void k_gather2_lsm(
    const int* __restrict__ rowptr, const unsigned int* __restrict__ partC,
    const float* __restrict__ dinv, const float* __restrict__ ha,
    const unsigned char* __restrict__ hb8, float* __restrict__ out) {
    long t = (long)blockIdx.x * 256 + threadIdx.x;
    int n = (int)(t >> 6);
    if (n >= NN) return;
    int lane = threadIdx.x & 63;
    int d = lane & 7, p = lane >> 3;
    int s = rowptr[n], e = rowptr[n + 1];
    float acc[4] = {0.f, 0.f, 0.f, 0.f};
    int j = s + p;
    for (; j + 8 < e; j += 16) {
        unsigned int u0 = partC[j], u1 = partC[j + 8];
        unsigned int v0 = *(const unsigned int*)(hb8 + (u0 & 0x1FFFF) * NCLS + d * 4);
        unsigned int v1 = *(const unsigned int*)(hb8 + (u1 & 0x1FFFF) * NCLS + d * 4);
        fp8x4_fma(v0, wdec(u0), acc);
        fp8x4_fma(v1, wdec(u1), acc);
    }
    if (j < e) {
        unsigned int u0 = partC[j];
        unsigned int v0 = *(const unsigned int*)(hb8 + (u0 & 0x1FFFF) * NCLS + d * 4);
        fp8x4_fma(v0, wdec(u0), acc);
    }
#pragma unroll
    for (int i = 0; i < 4; i++) {
        acc[i] += __shfl_xor(acc[i], 8);
        acc[i] += __shfl_xor(acc[i], 16);
        acc[i] += __shfl_xor(acc[i], 32);
    }
    float dn = dinv[n];
    float4 hv = *(const float4*)(ha + (long)n * NCLS + d * 4);
    float v0 = dn * acc[0] + hv.x;
    float v1 = dn * acc[1] + hv.y;
    float v2 = dn * acc[2] + hv.z;
    float v3 = dn * acc[3] + hv.w;
    float m = fmaxf(fmaxf(v0, v1), fmaxf(v2, v3));
    m = fmaxf(m, __shfl_xor(m, 1));
    m = fmaxf(m, __shfl_xor(m, 2));
    m = fmaxf(m, __shfl_xor(m, 4));
    float sum = __expf(v0 - m) + __expf(v1 - m) + __expf(v2 - m) + __expf(v3 - m);
    sum += __shfl_xor(sum, 1);
    sum += __shfl_xor(sum, 2);
    sum += __shfl_xor(sum, 4);
    float ls = logf(sum);
    if (p == 0) {
        float4 o; o.x = v0 - m - ls; o.y = v1 - m - ls;
        o.z = v2 - m - ls; o.w = v3 - m - ls;
        *(float4*)(out + (long)n * NCLS + d * 4) = o;
    }
}

extern "C" void kernel_launch(void* const* d_in, const int* in_sizes, int n_in,
                              void* d_out, int out_size, void* d_ws, size_t ws_size,
                              hipStream_t stream) {
    const float* x    = (const float*)d_in[0];
    const int*   ei   = (const int*)d_in[1];
    const float* ew   = (const float*)d_in[2];
    const float* W1_0 = (const float*)d_in[3];
    const float* W1_1 = (const float*)d_in[4];
    const float* b1   = (const float*)d_in[5];
    const float* W2_0 = (const float*)d_in[6];
    const float* W2_1 = (const float*)d_in[7];
    const float* b2   = (const float*)d_in[8];
    float* out = (float*)d_out;

    const int* row = ei;
    const int* col = ei + NE;

    char* ws = (char*)d_ws;
    int2*  partS     = (int2*)ws;                 ws += sizeof(int2) * (long)NBKT * CAP;
    unsigned int* partC = (unsigned int*)ws;      ws += sizeof(int) * NE;
    int*   bucketCursor = (int*)ws;               ws += sizeof(int) * NBKT;
    int*   bucketStart  = (int*)ws;               ws += sizeof(int) * NBKT;
    int*   rowptr    = (int*)ws;                  ws += sizeof(int) * (NN + 4);
    float* dinv      = (float*)ws;                ws += sizeof(float) * NN;
    float* xa        = (float*)ws;                ws += sizeof(float) * NN * HID;
    float* agg1      = (float*)ws;                ws += sizeof(float) * NN * HID;
    float* ha        = (float*)ws;                ws += sizeof(float) * NN * NCLS;
    unsigned char* xb8 = (unsigned char*)ws;      ws += sizeof(char) * NN * HID;
    unsigned char* hb8 = (unsigned char*)ws;      ws += sizeof(char) * NN * NCLS;

    k_zero_cur<<<(NBKT + 255) / 256, 256, 0, stream>>>(bucketCursor);
    k_partition<<<GP, 256, 0, stream>>>(row, col, ew, bucketCursor, partS);
    k_scan_buckets<<<1, 64, 0, stream>>>(bucketCursor, bucketStart);
    k_bucket_sort<<<NBKT, 256, 0, stream>>>(partS, bucketCursor, bucketStart,
                                            partC, rowptr, dinv);
    k_proj1<<<(NN + 127) / 128, 256, 0, stream>>>(x, W1_0, W1_1, b1, dinv, xa, xb8);
    {
        long th = (long)NN * 64;
        k_gather1<<<(int)((th + 255) / 256), 256, 0, stream>>>(rowptr, partC, dinv, xb8, agg1);
    }
    k_proj2<<<(NN + 255) / 256, 256, 0, stream>>>(xa, agg1, W2_0, W2_1, b2, dinv, ha, hb8);
    {
        long th = (long)NN * 64;
        k_gather2_lsm<<<(int)((th + 255) / 256), 256, 0, stream>>>(rowptr, partC, dinv, ha, hb8, out);
    }
}

// Round 10
// 249.148 us; speedup vs baseline: 1.1507x; 1.1507x over previous
//
#include <hip/hip_runtime.h>
#include <hip/hip_bf16.h>

// DFAChebNet forward.
//  layer: x@W0 + (agg(x)-x)@W1 + b == x@(W0-W1) + agg(x@W1) + b   (project first)
//  aggregation: CSR pull-gather; CSR built by LDS-staged counting sort.
//  R10: proj1 reverted to R8 body (thread-per-node, no LDS/barrier, register
//  double-buffered x loads) but with 128-thread blocks -> 782 blocks for
//  better CU balance. R9's atomic-reservation front-end kept.

#include <hip/hip_fp16.h>

constexpr int NN   = 100000;
constexpr int NE   = 1600000;
constexpr int FIN  = 128;
constexpr int HID  = 16;
constexpr int NCLS = 32;

constexpr int RB    = 256;                         // rows per bucket
constexpr int NBKT  = (NN + RB - 1) / RB;          // 391
constexpr int EPB   = 4096;                        // edges per partition block
constexpr int EPT   = EPB / 256;                   // 16 edges per thread
constexpr int GP    = (NE + EPB - 1) / EPB;        // 391
constexpr int CAP   = 8192;                        // bucket slot capacity (mean 4096)

typedef float f32x2 __attribute__((ext_vector_type(2)));

#if defined(__has_builtin)
#if __has_builtin(__builtin_amdgcn_cvt_pk_f32_fp8)
#define HAVE_CVT_FP8 1
#endif
#endif

// fp8 e4m3fn encode (RNE, subnormals flushed to 0, clamp at 448)
static __device__ __forceinline__ unsigned int f2e4m3(float f) {
    union { float f; unsigned int u; } v; v.f = f;
    unsigned int s = (v.u >> 24) & 0x80u;
    unsigned int au = v.u & 0x7fffffffu;
    if (au > 0x43E00000u) au = 0x43E00000u;        // clamp to 448
    au += 0x7ffffu + ((au >> 20) & 1u);            // RNE into 3-bit mantissa
    int e4 = (int)(au >> 23) - 120;                // 127-7
    unsigned int m = (au >> 20) & 7u;
    unsigned int byte = (e4 <= 0) ? 0u : (((unsigned int)e4 << 3) | m);
    return s | byte;
}
// 4 packed fp8 -> acc[0..3] += w * val
static __device__ __forceinline__ void fp8x4_fma(unsigned int v, float w, float* acc) {
#ifdef HAVE_CVT_FP8
    f32x2 lo = __builtin_amdgcn_cvt_pk_f32_fp8((int)v, false);
    f32x2 hi = __builtin_amdgcn_cvt_pk_f32_fp8((int)v, true);
    acc[0] += w * lo.x; acc[1] += w * lo.y;
    acc[2] += w * hi.x; acc[3] += w * hi.y;
#else
#pragma unroll
    for (int i = 0; i < 4; i++) {
        unsigned int b = (v >> (8 * i)) & 0xffu;
        float f = __int_as_float((int)(((b & 0x80u) << 24) | ((b & 0x7fu) << 20))) * 0x1p120f;
        acc[i] += w * f;
    }
#endif
}
// edge record: col(17 bits) | w(15 bits = signless bf16, RNE)
static __device__ __forceinline__ unsigned int wpack(float wf) {
    unsigned int b = __float_as_uint(wf) + 0x8000u;
    return (b >> 16) & 0x7fffu;
}
static __device__ __forceinline__ float wdec(unsigned int u) {
    return __uint_as_float((u >> 17) << 16);
}

// ---- zero the bucket cursors ----
__global__ void k_zero_cur(int* __restrict__ bucketCursor) {
    int i = blockIdx.x * blockDim.x + threadIdx.x;
    if (i < NBKT) bucketCursor[i] = 0;
}

// ---- pass B: LDS-staged partition; atomic reservation into slotted buffer ----
__global__ __launch_bounds__(256) void k_partition(
    const int* __restrict__ row, const int* __restrict__ col,
    const float* __restrict__ w, int* __restrict__ bucketCursor,
    int2* __restrict__ partS) {
    __shared__ int2 stage[EPB];              // 32KB
    __shared__ unsigned short sbkt[EPB];     // 8KB
    __shared__ int cnt[NBKT];
    __shared__ int lofs[NBKT];
    __shared__ int cursor[NBKT];
    __shared__ int gbase[NBKT];
    __shared__ int sa[512], sb[512];
    int tid = threadIdx.x;
    long ebase = (long)blockIdx.x * EPB;
    int rr[EPT]; int cc[EPT]; float wv[EPT];
#pragma unroll
    for (int i = 0; i < EPT; i++) {
        long e = ebase + i * 256 + tid;
        if (e < NE) { rr[i] = row[e]; cc[i] = col[e]; wv[i] = w[e]; }
        else rr[i] = -1;
    }
    for (int i = tid; i < NBKT; i += 256) cnt[i] = 0;
    __syncthreads();
#pragma unroll
    for (int i = 0; i < EPT; i++)
        if (rr[i] >= 0) atomicAdd(&cnt[rr[i] >> 8], 1);
    __syncthreads();
    for (int i = tid; i < 512; i += 256) sa[i] = (i < NBKT) ? cnt[i] : 0;
    __syncthreads();
    int* src = sa; int* dst = sb;
    for (int off = 1; off < 512; off <<= 1) {
        for (int i = tid; i < 512; i += 256)
            dst[i] = src[i] + ((i >= off) ? src[i - off] : 0);
        __syncthreads();
        int* t = src; src = dst; dst = t;
    }
    for (int i = tid; i < NBKT; i += 256) {
        int ex = src[i] - cnt[i];
        lofs[i] = ex;
        cursor[i] = ex;
        int go = (cnt[i] > 0) ? atomicAdd(&bucketCursor[i], cnt[i]) : 0;
        gbase[i] = i * CAP + go;
    }
    __syncthreads();
#pragma unroll
    for (int i = 0; i < EPT; i++) {
        if (rr[i] >= 0) {
            int b = rr[i] >> 8;
            int p = atomicAdd(&cursor[b], 1);
            int2 v;
            v.x = cc[i] | ((rr[i] & 255) << 17);
            v.y = __float_as_int(wv[i]);
            stage[p] = v;
            sbkt[p] = (unsigned short)b;
        }
    }
    __syncthreads();
    int total = (int)min((long)EPB, NE - ebase);
    for (int i = tid; i < total; i += 256) {
        int b = sbkt[i];
        partS[gbase[b] + (i - lofs[b])] = stage[i];
    }
}

// ---- exclusive scan of the 391 bucket totals (one wave) ----
__global__ void k_scan_buckets(const int* __restrict__ bucketCursor,
                               int* __restrict__ bucketStart) {
    int lane = threadIdx.x;  // 64 threads
    int v[8], e[8];
    int s = 0;
#pragma unroll
    for (int t = 0; t < 8; t++) {
        int idx = lane * 8 + t;
        v[t] = (idx < NBKT) ? bucketCursor[idx] : 0;
        e[t] = s;
        s += v[t];
    }
    int sc = s;
    for (int off = 1; off < 64; off <<= 1) {
        int up = __shfl_up(sc, off, 64);
        if (lane >= off) sc += up;
    }
    int excl = sc - s;
#pragma unroll
    for (int t = 0; t < 8; t++) {
        int idx = lane * 8 + t;
        if (idx < NBKT) bucketStart[idx] = excl + e[t];
    }
}

// ---- pass C: per-bucket sort by row; emits packed 4B CSR, rowptr, dinv ----
__global__ __launch_bounds__(256) void k_bucket_sort(
    const int2* __restrict__ partS, const int* __restrict__ bucketCursor,
    const int* __restrict__ bucketStart,
    unsigned int* __restrict__ partC, int* __restrict__ rowptr,
    float* __restrict__ dinv) {
    __shared__ int2 stage[CAP];          // 64KB
    __shared__ int hist[RB];
    __shared__ int cursor[RB];
    __shared__ int wtot[4];
    int b = blockIdx.x;
    int tid = threadIdx.x;
    int start = bucketStart[b];
    int count = bucketCursor[b];
    const int2* src = partS + (long)b * CAP;
    hist[tid] = 0;
    __syncthreads();
    for (int i = tid; i < count; i += 256)
        atomicAdd(&hist[(src[i].x >> 17) & 255], 1);
    __syncthreads();
    int lane = tid & 63, wv = tid >> 6;
    int v = hist[tid];
    int sc = v;
#pragma unroll
    for (int off = 1; off < 64; off <<= 1) {
        int up = __shfl_up(sc, off, 64);
        if (lane >= off) sc += up;
    }
    if (lane == 63) wtot[wv] = sc;
    __syncthreads();
    int add = 0;
    for (int w2 = 0; w2 < wv; w2++) add += wtot[w2];
    int ex = sc + add - v;
    int node = b * RB + tid;
    if (node <= NN) rowptr[node] = start + ex;   // node==NN -> NE (last bucket)
    cursor[tid] = ex;
    __syncthreads();
    for (int i = tid; i < count; i += 256) {
        int2 p = src[i];
        int rl = (p.x >> 17) & 255;
        int pos = atomicAdd(&cursor[rl], 1);
        int2 c; c.x = p.x & 0x1FFFF; c.y = p.y;
        if (pos < CAP) stage[pos] = c;
    }
    __syncthreads();
    {
        int rend = cursor[tid];
        float d = 0.f;
        for (int i = ex; i < rend; i++) d += __int_as_float(stage[i].y);
        if (node < NN) dinv[node] = d > 0.f ? rsqrtf(d) : 0.f;
    }
    for (int i = tid; i < count; i += 256)
        if (i < CAP) {
            int2 p = stage[i];
            partC[start + i] = (unsigned int)p.x | (wpack(__int_as_float(p.y)) << 17);
        }
}

// xa = x@(W1_0-W1_1)+b1 (fp32) ; xb' = dinv[n] * (x@W1_1) (fp8 e4m3).
// 1 thread = 1 node; W wave-uniform (s_load); x via register-double-buffered
// float4 reads. 128-thread blocks (782 blocks) for CU load balance.
__global__ __launch_bounds__(128) void k_proj1(
    const float* __restrict__ x, const float* __restrict__ W0,
    const float* __restrict__ W1, const float* __restrict__ b1,
    const float* __restrict__ dinv,
    float* __restrict__ xa, unsigned char* __restrict__ xb8) {
    long t = (long)blockIdx.x * 128 + threadIdx.x;
    bool valid = t < NN;
    long n = valid ? t : 0;
    const float4* xg = (const float4*)x + n * 32;
    float accA[HID], accB[HID];
#pragma unroll
    for (int o = 0; o < HID; o++) { accA[o] = 0.f; accB[o] = 0.f; }
    float4 bufA[8], bufB[8];
#pragma unroll
    for (int m = 0; m < 8; m++) bufA[m] = xg[m];          // chunk 0
#pragma unroll
    for (int m = 0; m < 8; m++) bufB[m] = xg[8 + m];      // chunk 1

#define PROJ1_CHUNK(BUF, C)                                            \
    {                                                                   \
        const float* W0p = W0 + (C) * 32 * HID;                         \
        const float* W1p = W1 + (C) * 32 * HID;                         \
        _Pragma("unroll")                                               \
        for (int m = 0; m < 8; m++) {                                   \
            float xv[4] = {BUF[m].x, BUF[m].y, BUF[m].z, BUF[m].w};     \
            _Pragma("unroll")                                           \
            for (int q = 0; q < 4; q++) {                               \
                int k = m * 4 + q;                                      \
                _Pragma("unroll")                                       \
                for (int o = 0; o < HID; o++) accA[o] += xv[q] * W0p[k * HID + o]; \
                _Pragma("unroll")                                       \
                for (int o = 0; o < HID; o++) accB[o] += xv[q] * W1p[k * HID + o]; \
            }                                                           \
        }                                                               \
    }

    PROJ1_CHUNK(bufA, 0)
#pragma unroll
    for (int m = 0; m < 8; m++) bufA[m] = xg[16 + m];     // chunk 2
    PROJ1_CHUNK(bufB, 1)
#pragma unroll
    for (int m = 0; m < 8; m++) bufB[m] = xg[24 + m];     // chunk 3
    PROJ1_CHUNK(bufA, 2)
    PROJ1_CHUNK(bufB, 3)
#undef PROJ1_CHUNK

    if (!valid) return;
    float4* xap = (float4*)(xa + n * HID);
#pragma unroll
    for (int q = 0; q < 4; q++) {
        float4 va;
        va.x = accA[4*q+0] - accB[4*q+0] + b1[4*q+0];
        va.y = accA[4*q+1] - accB[4*q+1] + b1[4*q+1];
        va.z = accA[4*q+2] - accB[4*q+2] + b1[4*q+2];
        va.w = accA[4*q+3] - accB[4*q+3] + b1[4*q+3];
        xap[q] = va;
    }
    float dn = dinv[n];
    unsigned int pk[4];
#pragma unroll
    for (int q = 0; q < 4; q++)
        pk[q] = f2e4m3(dn * accB[4*q+0]) | (f2e4m3(dn * accB[4*q+1]) << 8)
              | (f2e4m3(dn * accB[4*q+2]) << 16) | (f2e4m3(dn * accB[4*q+3]) << 24);
    *(uint4*)(xb8 + n * HID) = make_uint4(pk[0], pk[1], pk[2], pk[3]);
}

// agg1[n,:] = dinv[n] * sum_j w_j * xb'[c_j,:].
// 1 wave = 1 node; lane = (parity p 0..15, dword d 0..3); 16 lines in flight.
__global__ __launch_bounds__(256) void k_gather1(
    const int* __restrict__ rowptr, const unsigned int* __restrict__ partC,
    const float* __restrict__ dinv, const unsigned char* __restrict__ xb8,
    float* __restrict__ agg1) {
    long t = (long)blockIdx.x * 256 + threadIdx.x;
    int n = (int)(t >> 6);
    if (n >= NN) return;
    int lane = threadIdx.x & 63;
    int d = lane & 3, p = lane >> 2;
    int s = rowptr[n], e = rowptr[n + 1];
    float acc[4] = {0.f, 0.f, 0.f, 0.f};
    for (int j = s + p; j < e; j += 16) {
        unsigned int u = partC[j];
        unsigned int v = *(const unsigned int*)(xb8 + (u & 0x1FFFF) * HID + d * 4);
        fp8x4_fma(v, wdec(u), acc);
    }
#pragma unroll
    for (int i = 0; i < 4; i++) {
        acc[i] += __shfl_xor(acc[i], 4);
        acc[i] += __shfl_xor(acc[i], 8);
        acc[i] += __shfl_xor(acc[i], 16);
        acc[i] += __shfl_xor(acc[i], 32);
    }
    if (p == 0) {
        float dn = dinv[n];
        float4 o; o.x = dn * acc[0]; o.y = dn * acc[1];
        o.z = dn * acc[2]; o.w = dn * acc[3];
        *(float4*)(agg1 + (long)n * HID + d * 4) = o;
    }
}

// h = relu(xa+agg1); ha = h@(W2_0-W2_1)+b2 (fp32) ; hb' = dinv*h@W2_1 (fp8).
__global__ __launch_bounds__(256) void k_proj2(
    const float* __restrict__ xa, const float* __restrict__ agg1,
    const float* __restrict__ W0, const float* __restrict__ W1,
    const float* __restrict__ b2, const float* __restrict__ dinv,
    float* __restrict__ ha, unsigned char* __restrict__ hb8) {
    long n = (long)blockIdx.x * 256 + threadIdx.x;
    if (n >= NN) return;
    float h[HID];
    const float4* xap = (const float4*)(xa + n * HID);
    const float4* agp = (const float4*)(agg1 + n * HID);
#pragma unroll
    for (int q = 0; q < 4; q++) {
        float4 a = xap[q], g = agp[q];
        h[4*q+0] = fmaxf(a.x + g.x, 0.f);
        h[4*q+1] = fmaxf(a.y + g.y, 0.f);
        h[4*q+2] = fmaxf(a.z + g.z, 0.f);
        h[4*q+3] = fmaxf(a.w + g.w, 0.f);
    }
    float accA[NCLS], accB[NCLS];
#pragma unroll
    for (int o = 0; o < NCLS; o++) { accA[o] = 0.f; accB[o] = 0.f; }
#pragma unroll 2
    for (int k = 0; k < HID; k++) {
        float hk = h[k];
#pragma unroll
        for (int o = 0; o < NCLS; o++) accA[o] += hk * W0[k * NCLS + o];
#pragma unroll
        for (int o = 0; o < NCLS; o++) accB[o] += hk * W1[k * NCLS + o];
    }
    float4* hap = (float4*)(ha + n * NCLS);
#pragma unroll
    for (int q = 0; q < 8; q++) {
        float4 va;
        va.x = accA[4*q+0] - accB[4*q+0] + b2[4*q+0];
        va.y = accA[4*q+1] - accB[4*q+1] + b2[4*q+1];
        va.z = accA[4*q+2] - accB[4*q+2] + b2[4*q+2];
        va.w = accA[4*q+3] - accB[4*q+3] + b2[4*q+3];
        hap[q] = va;
    }
    float dn = dinv[n];
    unsigned int pk[8];
#pragma unroll
    for (int q = 0; q < 8; q++)
        pk[q] = f2e4m3(dn * accB[4*q+0]) | (f2e4m3(dn * accB[4*q+1]) << 8)
              | (f2e4m3(dn * accB[4*q+2]) << 16) | (f2e4m3(dn * accB[4*q+3]) << 24);
    uint4* hbp = (uint4*)(hb8 + n * NCLS);
    hbp[0] = make_uint4(pk[0], pk[1], pk[2], pk[3]);
    hbp[1] = make_uint4(pk[4], pk[5], pk[6], pk[7]);
}

// out[n,:] = log_softmax(ha[n,:] + dinv[n]*sum_j w_j*hb'[c_j,:]).
// 1 wave = 1 node; lane = (parity p 0..7, dword d 0..7); unroll 2.
__global__ __launch_bounds__(256) void k_gather2_lsm(
    const int* __restrict__ rowptr, const unsigned int* __restrict__ partC,
    const float* __restrict__ dinv, const float* __restrict__ ha,
    const unsigned char* __restrict__ hb8, float* __restrict__ out) {
    long t = (long)blockIdx.x * 256 + threadIdx.x;
    int n = (int)(t >> 6);
    if (n >= NN) return;
    int lane = threadIdx.x & 63;
    int d = lane & 7, p = lane >> 3;
    int s = rowptr[n], e = rowptr[n + 1];
    float acc[4] = {0.f, 0.f, 0.f, 0.f};
    int j = s + p;
    for (; j + 8 < e; j += 16) {
        unsigned int u0 = partC[j], u1 = partC[j + 8];
        unsigned int v0 = *(const unsigned int*)(hb8 + (u0 & 0x1FFFF) * NCLS + d * 4);
        unsigned int v1 = *(const unsigned int*)(hb8 + (u1 & 0x1FFFF) * NCLS + d * 4);
        fp8x4_fma(v0, wdec(u0), acc);
        fp8x4_fma(v1, wdec(u1), acc);
    }
    if (j < e) {
        unsigned int u0 = partC[j];
        unsigned int v0 = *(const unsigned int*)(hb8 + (u0 & 0x1FFFF) * NCLS + d * 4);
        fp8x4_fma(v0, wdec(u0), acc);
    }
#pragma unroll
    for (int i = 0; i < 4; i++) {
        acc[i] += __shfl_xor(acc[i], 8);
        acc[i] += __shfl_xor(acc[i], 16);
        acc[i] += __shfl_xor(acc[i], 32);
    }
    float dn = dinv[n];
    float4 hv = *(const float4*)(ha + (long)n * NCLS + d * 4);
    float v0 = dn * acc[0] + hv.x;
    float v1 = dn * acc[1] + hv.y;
    float v2 = dn * acc[2] + hv.z;
    float v3 = dn * acc[3] + hv.w;
    float m = fmaxf(fmaxf(v0, v1), fmaxf(v2, v3));
    m = fmaxf(m, __shfl_xor(m, 1));
    m = fmaxf(m, __shfl_xor(m, 2));
    m = fmaxf(m, __shfl_xor(m, 4));
    float sum = __expf(v0 - m) + __expf(v1 - m) + __expf(v2 - m) + __expf(v3 - m);
    sum += __shfl_xor(sum, 1);
    sum += __shfl_xor(sum, 2);
    sum += __shfl_xor(sum, 4);
    float ls = logf(sum);
    if (p == 0) {
        float4 o; o.x = v0 - m - ls; o.y = v1 - m - ls;
        o.z = v2 - m - ls; o.w = v3 - m - ls;
        *(float4*)(out + (long)n * NCLS + d * 4) = o;
    }
}

extern "C" void kernel_launch(void* const* d_in, const int* in_sizes, int n_in,
                              void* d_out, int out_size, void* d_ws, size_t ws_size,
                              hipStream_t stream) {
    const float* x    = (const float*)d_in[0];
    const int*   ei   = (const int*)d_in[1];
    const float* ew   = (const float*)d_in[2];
    const float* W1_0 = (const float*)d_in[3];
    const float* W1_1 = (const float*)d_in[4];
    const float* b1   = (const float*)d_in[5];
    const float* W2_0 = (const float*)d_in[6];
    const float* W2_1 = (const float*)d_in[7];
    const float* b2   = (const float*)d_in[8];
    float* out = (float*)d_out;

    const int* row = ei;
    const int* col = ei + NE;

    char* ws = (char*)d_ws;
    int2*  partS     = (int2*)ws;                 ws += sizeof(int2) * (long)NBKT * CAP;
    unsigned int* partC = (unsigned int*)ws;      ws += sizeof(int) * NE;
    int*   bucketCursor = (int*)ws;               ws += sizeof(int) * NBKT;
    int*   bucketStart  = (int*)ws;               ws += sizeof(int) * NBKT;
    int*   rowptr    = (int*)ws;                  ws += sizeof(int) * (NN + 4);
    float* dinv      = (float*)ws;                ws += sizeof(float) * NN;
    float* xa        = (float*)ws;                ws += sizeof(float) * NN * HID;
    float* agg1      = (float*)ws;                ws += sizeof(float) * NN * HID;
    float* ha        = (float*)ws;                ws += sizeof(float) * NN * NCLS;
    unsigned char* xb8 = (unsigned char*)ws;      ws += sizeof(char) * NN * HID;
    unsigned char* hb8 = (unsigned char*)ws;      ws += sizeof(char) * NN * NCLS;

    k_zero_cur<<<(NBKT + 255) / 256, 256, 0, stream>>>(bucketCursor);
    k_partition<<<GP, 256, 0, stream>>>(row, col, ew, bucketCursor, partS);
    k_scan_buckets<<<1, 64, 0, stream>>>(bucketCursor, bucketStart);
    k_bucket_sort<<<NBKT, 256, 0, stream>>>(partS, bucketCursor, bucketStart,
                                            partC, rowptr, dinv);
    k_proj1<<<(NN + 127) / 128, 128, 0, stream>>>(x, W1_0, W1_1, b1, dinv, xa, xb8);
    {
        long th = (long)NN * 64;
        k_gather1<<<(int)((th + 255) / 256), 256, 0, stream>>>(rowptr, partC, dinv, xb8, agg1);
    }
    k_proj2<<<(NN + 255) / 256, 256, 0, stream>>>(xa, agg1, W2_0, W2_1, b2, dinv, ha, hb8);
    {
        long th = (long)NN * 64;
        k_gather2_lsm<<<(int)((th + 255) / 256), 256, 0, stream>>>(rowptr, partC, dinv, ha, hb8, out);
    }
}

// Round 11
// 232.511 us; speedup vs baseline: 1.2331x; 1.0716x over previous
//
#include <hip/hip_runtime.h>
#include <hip/hip_bf16.h>

// DFAChebNet forward.
//  layer: x@W0 + (agg(x)-x)@W1 + b == x@(W0-W1) + agg(x@W1) + b   (project first)
//  aggregation: CSR pull-gather; CSR built by LDS-staged counting sort.
//  R11: proj1 via mfma_f32_16x16x32_bf16 -- 1 wave = 16-node tile; W frags
//  held in VGPRs (loaded once, no scalar-path streaming), x = 8 float4
//  loads/lane upfront, 8 MFMAs, epilogue from C layout (col=lane&15,
//  row=quad*4+reg). Grid = 6250 waves (~6/SIMD) vs 1562 before.

#include <hip/hip_fp16.h>

constexpr int NN   = 100000;
constexpr int NE   = 1600000;
constexpr int FIN  = 128;
constexpr int HID  = 16;
constexpr int NCLS = 32;

constexpr int RB    = 256;                         // rows per bucket
constexpr int NBKT  = (NN + RB - 1) / RB;          // 391
constexpr int EPB   = 4096;                        // edges per partition block
constexpr int EPT   = EPB / 256;                   // 16 edges per thread
constexpr int GP    = (NE + EPB - 1) / EPB;        // 391
constexpr int CAP   = 8192;                        // bucket slot capacity (mean 4096)
constexpr int NTILE = NN / 16;                     // 6250 MFMA tiles (exact)

typedef float f32x2 __attribute__((ext_vector_type(2)));
typedef float f32x4 __attribute__((ext_vector_type(4)));
typedef short bf16x8 __attribute__((ext_vector_type(8)));

#if defined(__has_builtin)
#if __has_builtin(__builtin_amdgcn_cvt_pk_f32_fp8)
#define HAVE_CVT_FP8 1
#endif
#endif

// fp8 e4m3fn encode (RNE, subnormals flushed to 0, clamp at 448)
static __device__ __forceinline__ unsigned int f2e4m3(float f) {
    union { float f; unsigned int u; } v; v.f = f;
    unsigned int s = (v.u >> 24) & 0x80u;
    unsigned int au = v.u & 0x7fffffffu;
    if (au > 0x43E00000u) au = 0x43E00000u;        // clamp to 448
    au += 0x7ffffu + ((au >> 20) & 1u);            // RNE into 3-bit mantissa
    int e4 = (int)(au >> 23) - 120;                // 127-7
    unsigned int m = (au >> 20) & 7u;
    unsigned int byte = (e4 <= 0) ? 0u : (((unsigned int)e4 << 3) | m);
    return s | byte;
}
// 4 packed fp8 -> acc[0..3] += w * val
static __device__ __forceinline__ void fp8x4_fma(unsigned int v, float w, float* acc) {
#ifdef HAVE_CVT_FP8
    f32x2 lo = __builtin_amdgcn_cvt_pk_f32_fp8((int)v, false);
    f32x2 hi = __builtin_amdgcn_cvt_pk_f32_fp8((int)v, true);
    acc[0] += w * lo.x; acc[1] += w * lo.y;
    acc[2] += w * hi.x; acc[3] += w * hi.y;
#else
#pragma unroll
    for (int i = 0; i < 4; i++) {
        unsigned int b = (v >> (8 * i)) & 0xffu;
        float f = __int_as_float((int)(((b & 0x80u) << 24) | ((b & 0x7fu) << 20))) * 0x1p120f;
        acc[i] += w * f;
    }
#endif
}
// bf16 RNE
static __device__ __forceinline__ unsigned short f2bf(float f) {
    union { float f; unsigned int u; } v; v.f = f;
    unsigned int r = v.u + 0x7fffu + ((v.u >> 16) & 1u);
    return (unsigned short)(r >> 16);
}
// edge record: col(17 bits) | w(15 bits = signless bf16, RNE)
static __device__ __forceinline__ unsigned int wpack(float wf) {
    unsigned int b = __float_as_uint(wf) + 0x8000u;
    return (b >> 16) & 0x7fffu;
}
static __device__ __forceinline__ float wdec(unsigned int u) {
    return __uint_as_float((u >> 17) << 16);
}

// ---- zero the bucket cursors ----
__global__ void k_zero_cur(int* __restrict__ bucketCursor) {
    int i = blockIdx.x * blockDim.x + threadIdx.x;
    if (i < NBKT) bucketCursor[i] = 0;
}

// ---- pass B: LDS-staged partition; atomic reservation into slotted buffer ----
__global__ __launch_bounds__(256) void k_partition(
    const int* __restrict__ row, const int* __restrict__ col,
    const float* __restrict__ w, int* __restrict__ bucketCursor,
    int2* __restrict__ partS) {
    __shared__ int2 stage[EPB];              // 32KB
    __shared__ unsigned short sbkt[EPB];     // 8KB
    __shared__ int cnt[NBKT];
    __shared__ int lofs[NBKT];
    __shared__ int cursor[NBKT];
    __shared__ int gbase[NBKT];
    __shared__ int sa[512], sb[512];
    int tid = threadIdx.x;
    long ebase = (long)blockIdx.x * EPB;
    int rr[EPT]; int cc[EPT]; float wv[EPT];
#pragma unroll
    for (int i = 0; i < EPT; i++) {
        long e = ebase + i * 256 + tid;
        if (e < NE) { rr[i] = row[e]; cc[i] = col[e]; wv[i] = w[e]; }
        else rr[i] = -1;
    }
    for (int i = tid; i < NBKT; i += 256) cnt[i] = 0;
    __syncthreads();
#pragma unroll
    for (int i = 0; i < EPT; i++)
        if (rr[i] >= 0) atomicAdd(&cnt[rr[i] >> 8], 1);
    __syncthreads();
    for (int i = tid; i < 512; i += 256) sa[i] = (i < NBKT) ? cnt[i] : 0;
    __syncthreads();
    int* src = sa; int* dst = sb;
    for (int off = 1; off < 512; off <<= 1) {
        for (int i = tid; i < 512; i += 256)
            dst[i] = src[i] + ((i >= off) ? src[i - off] : 0);
        __syncthreads();
        int* t = src; src = dst; dst = t;
    }
    for (int i = tid; i < NBKT; i += 256) {
        int ex = src[i] - cnt[i];
        lofs[i] = ex;
        cursor[i] = ex;
        int go = (cnt[i] > 0) ? atomicAdd(&bucketCursor[i], cnt[i]) : 0;
        gbase[i] = i * CAP + go;
    }
    __syncthreads();
#pragma unroll
    for (int i = 0; i < EPT; i++) {
        if (rr[i] >= 0) {
            int b = rr[i] >> 8;
            int p = atomicAdd(&cursor[b], 1);
            int2 v;
            v.x = cc[i] | ((rr[i] & 255) << 17);
            v.y = __float_as_int(wv[i]);
            stage[p] = v;
            sbkt[p] = (unsigned short)b;
        }
    }
    __syncthreads();
    int total = (int)min((long)EPB, NE - ebase);
    for (int i = tid; i < total; i += 256) {
        int b = sbkt[i];
        partS[gbase[b] + (i - lofs[b])] = stage[i];
    }
}

// ---- exclusive scan of the 391 bucket totals (one wave) ----
__global__ void k_scan_buckets(const int* __restrict__ bucketCursor,
                               int* __restrict__ bucketStart) {
    int lane = threadIdx.x;  // 64 threads
    int v[8], e[8];
    int s = 0;
#pragma unroll
    for (int t = 0; t < 8; t++) {
        int idx = lane * 8 + t;
        v[t] = (idx < NBKT) ? bucketCursor[idx] : 0;
        e[t] = s;
        s += v[t];
    }
    int sc = s;
    for (int off = 1; off < 64; off <<= 1) {
        int up = __shfl_up(sc, off, 64);
        if (lane >= off) sc += up;
    }
    int excl = sc - s;
#pragma unroll
    for (int t = 0; t < 8; t++) {
        int idx = lane * 8 + t;
        if (idx < NBKT) bucketStart[idx] = excl + e[t];
    }
}

// ---- pass C: per-bucket sort by row; emits packed 4B CSR, rowptr, dinv ----
__global__ __launch_bounds__(256) void k_bucket_sort(
    const int2* __restrict__ partS, const int* __restrict__ bucketCursor,
    const int* __restrict__ bucketStart,
    unsigned int* __restrict__ partC, int* __restrict__ rowptr,
    float* __restrict__ dinv) {
    __shared__ int2 stage[CAP];          // 64KB
    __shared__ int hist[RB];
    __shared__ int cursor[RB];
    __shared__ int wtot[4];
    int b = blockIdx.x;
    int tid = threadIdx.x;
    int start = bucketStart[b];
    int count = bucketCursor[b];
    const int2* src = partS + (long)b * CAP;
    hist[tid] = 0;
    __syncthreads();
    for (int i = tid; i < count; i += 256)
        atomicAdd(&hist[(src[i].x >> 17) & 255], 1);
    __syncthreads();
    int lane = tid & 63, wv = tid >> 6;
    int v = hist[tid];
    int sc = v;
#pragma unroll
    for (int off = 1; off < 64; off <<= 1) {
        int up = __shfl_up(sc, off, 64);
        if (lane >= off) sc += up;
    }
    if (lane == 63) wtot[wv] = sc;
    __syncthreads();
    int add = 0;
    for (int w2 = 0; w2 < wv; w2++) add += wtot[w2];
    int ex = sc + add - v;
    int node = b * RB + tid;
    if (node <= NN) rowptr[node] = start + ex;   // node==NN -> NE (last bucket)
    cursor[tid] = ex;
    __syncthreads();
    for (int i = tid; i < count; i += 256) {
        int2 p = src[i];
        int rl = (p.x >> 17) & 255;
        int pos = atomicAdd(&cursor[rl], 1);
        int2 c; c.x = p.x & 0x1FFFF; c.y = p.y;
        if (pos < CAP) stage[pos] = c;
    }
    __syncthreads();
    {
        int rend = cursor[tid];
        float d = 0.f;
        for (int i = ex; i < rend; i++) d += __int_as_float(stage[i].y);
        if (node < NN) dinv[node] = d > 0.f ? rsqrtf(d) : 0.f;
    }
    for (int i = tid; i < count; i += 256)
        if (i < CAP) {
            int2 p = stage[i];
            partC[start + i] = (unsigned int)p.x | (wpack(__int_as_float(p.y)) << 17);
        }
}

// xa = x@(W1_0-W1_1)+b1 (fp32) ; xb' = dinv[n] * (x@W1_1) (fp8 e4m3).
// MFMA 16x16x32 bf16: 1 wave = 16 nodes. W frags in VGPRs (built once);
// A = 8 float4 loads/lane; acc0 = x@W1_0, acc1 = x@W1_1.
__global__ __launch_bounds__(256) void k_proj1(
    const float* __restrict__ x, const float* __restrict__ W0,
    const float* __restrict__ W1, const float* __restrict__ b1,
    const float* __restrict__ dinv,
    float* __restrict__ xa, unsigned char* __restrict__ xb8) {
    int wid = (int)(((long)blockIdx.x * 256 + threadIdx.x) >> 6);   // tile id
    if (wid >= NTILE) return;
    int lane = threadIdx.x & 63;
    int col = lane & 15, quad = lane >> 4;

    // B fragments: B[k = kb*32 + quad*8 + j][n = col], once per wave.
    bf16x8 bfrag[2][4];
#pragma unroll
    for (int mat = 0; mat < 2; mat++) {
        const float* W = mat ? W1 : W0;
#pragma unroll
        for (int kb = 0; kb < 4; kb++) {
            bf16x8 f;
#pragma unroll
            for (int j = 0; j < 8; j++)
                f[j] = (short)f2bf(W[(kb * 32 + quad * 8 + j) * HID + col]);
            bfrag[mat][kb] = f;
        }
    }

    // A: lane's share of the tile = x[node = wid*16+col][quad*8 .. ] per kblock
    const float* xrow = x + ((long)wid * 16 + col) * FIN + quad * 8;
    float4 xb[8];
#pragma unroll
    for (int kb = 0; kb < 4; kb++) {
        xb[2 * kb]     = *(const float4*)(xrow + kb * 32);
        xb[2 * kb + 1] = *(const float4*)(xrow + kb * 32 + 4);
    }
    f32x4 acc0 = {0.f, 0.f, 0.f, 0.f}, acc1 = {0.f, 0.f, 0.f, 0.f};
#pragma unroll
    for (int kb = 0; kb < 4; kb++) {
        float4 a0 = xb[2 * kb], a1 = xb[2 * kb + 1];
        bf16x8 af;
        af[0] = (short)f2bf(a0.x); af[1] = (short)f2bf(a0.y);
        af[2] = (short)f2bf(a0.z); af[3] = (short)f2bf(a0.w);
        af[4] = (short)f2bf(a1.x); af[5] = (short)f2bf(a1.y);
        af[6] = (short)f2bf(a1.z); af[7] = (short)f2bf(a1.w);
        acc0 = __builtin_amdgcn_mfma_f32_16x16x32_bf16(af, bfrag[0][kb], acc0, 0, 0, 0);
        acc1 = __builtin_amdgcn_mfma_f32_16x16x32_bf16(af, bfrag[1][kb], acc1, 0, 0, 0);
    }

    // C layout: col = lane&15, row = quad*4 + r
    float b1v = b1[col];
#pragma unroll
    for (int r = 0; r < 4; r++) {
        long node = (long)wid * 16 + quad * 4 + r;
        float a0 = acc0[r], a1 = acc1[r];
        xa[node * HID + col] = a0 - a1 + b1v;
        float dn = dinv[node];
        xb8[node * HID + col] = (unsigned char)f2e4m3(dn * a1);
    }
}

// agg1[n,:] = dinv[n] * sum_j w_j * xb'[c_j,:].
// 1 wave = 1 node; lane = (parity p 0..15, dword d 0..3); 16 lines in flight.
__global__ __launch_bounds__(256) void k_gather1(
    const int* __restrict__ rowptr, const unsigned int* __restrict__ partC,
    const float* __restrict__ dinv, const unsigned char* __restrict__ xb8,
    float* __restrict__ agg1) {
    long t = (long)blockIdx.x * 256 + threadIdx.x;
    int n = (int)(t >> 6);
    if (n >= NN) return;
    int lane = threadIdx.x & 63;
    int d = lane & 3, p = lane >> 2;
    int s = rowptr[n], e = rowptr[n + 1];
    float acc[4] = {0.f, 0.f, 0.f, 0.f};
    for (int j = s + p; j < e; j += 16) {
        unsigned int u = partC[j];
        unsigned int v = *(const unsigned int*)(xb8 + (u & 0x1FFFF) * HID + d * 4);
        fp8x4_fma(v, wdec(u), acc);
    }
#pragma unroll
    for (int i = 0; i < 4; i++) {
        acc[i] += __shfl_xor(acc[i], 4);
        acc[i] += __shfl_xor(acc[i], 8);
        acc[i] += __shfl_xor(acc[i], 16);
        acc[i] += __shfl_xor(acc[i], 32);
    }
    if (p == 0) {
        float dn = dinv[n];
        float4 o; o.x = dn * acc[0]; o.y = dn * acc[1];
        o.z = dn * acc[2]; o.w = dn * acc[3];
        *(float4*)(agg1 + (long)n * HID + d * 4) = o;
    }
}

// h = relu(xa+agg1); ha = h@(W2_0-W2_1)+b2 (fp32) ; hb' = dinv*h@W2_1 (fp8).
__global__ __launch_bounds__(256) void k_proj2(
    const float* __restrict__ xa, const float* __restrict__ agg1,
    const float* __restrict__ W0, const float* __restrict__ W1,
    const float* __restrict__ b2, const float* __restrict__ dinv,
    float* __restrict__ ha, unsigned char* __restrict__ hb8) {
    long n = (long)blockIdx.x * 256 + threadIdx.x;
    if (n >= NN) return;
    float h[HID];
    const float4* xap = (const float4*)(xa + n * HID);
    const float4* agp = (const float4*)(agg1 + n * HID);
#pragma unroll
    for (int q = 0; q < 4; q++) {
        float4 a = xap[q], g = agp[q];
        h[4*q+0] = fmaxf(a.x + g.x, 0.f);
        h[4*q+1] = fmaxf(a.y + g.y, 0.f);
        h[4*q+2] = fmaxf(a.z + g.z, 0.f);
        h[4*q+3] = fmaxf(a.w + g.w, 0.f);
    }
    float accA[NCLS], accB[NCLS];
#pragma unroll
    for (int o = 0; o < NCLS; o++) { accA[o] = 0.f; accB[o] = 0.f; }
#pragma unroll 2
    for (int k = 0; k < HID; k++) {
        float hk = h[k];
#pragma unroll
        for (int o = 0; o < NCLS; o++) accA[o] += hk * W0[k * NCLS + o];
#pragma unroll
        for (int o = 0; o < NCLS; o++) accB[o] += hk * W1[k * NCLS + o];
    }
    float4* hap = (float4*)(ha + n * NCLS);
#pragma unroll
    for (int q = 0; q < 8; q++) {
        float4 va;
        va.x = accA[4*q+0] - accB[4*q+0] + b2[4*q+0];
        va.y = accA[4*q+1] - accB[4*q+1] + b2[4*q+1];
        va.z = accA[4*q+2] - accB[4*q+2] + b2[4*q+2];
        va.w = accA[4*q+3] - accB[4*q+3] + b2[4*q+3];
        hap[q] = va;
    }
    float dn = dinv[n];
    unsigned int pk[8];
#pragma unroll
    for (int q = 0; q < 8; q++)
        pk[q] = f2e4m3(dn * accB[4*q+0]) | (f2e4m3(dn * accB[4*q+1]) << 8)
              | (f2e4m3(dn * accB[4*q+2]) << 16) | (f2e4m3(dn * accB[4*q+3]) << 24);
    uint4* hbp = (uint4*)(hb8 + n * NCLS);
    hbp[0] = make_uint4(pk[0], pk[1], pk[2], pk[3]);
    hbp[1] = make_uint4(pk[4], pk[5], pk[6], pk[7]);
}

// out[n,:] = log_softmax(ha[n,:] + dinv[n]*sum_j w_j*hb'[c_j,:]).
// 1 wave = 1 node; lane = (parity p 0..7, dword d 0..7); unroll 2.
__global__ __launch_bounds__(256) void k_gather2_lsm(
    const int* __restrict__ rowptr, const unsigned int* __restrict__ partC,
    const float* __restrict__ dinv, const float* __restrict__ ha,
    const unsigned char* __restrict__ hb8, float* __restrict__ out) {
    long t = (long)blockIdx.x * 256 + threadIdx.x;
    int n = (int)(t >> 6);
    if (n >= NN) return;
    int lane = threadIdx.x & 63;
    int d = lane & 7, p = lane >> 3;
    int s = rowptr[n], e = rowptr[n + 1];
    float acc[4] = {0.f, 0.f, 0.f, 0.f};
    int j = s + p;
    for (; j + 8 < e; j += 16) {
        unsigned int u0 = partC[j], u1 = partC[j + 8];
        unsigned int v0 = *(const unsigned int*)(hb8 + (u0 & 0x1FFFF) * NCLS + d * 4);
        unsigned int v1 = *(const unsigned int*)(hb8 + (u1 & 0x1FFFF) * NCLS + d * 4);
        fp8x4_fma(v0, wdec(u0), acc);
        fp8x4_fma(v1, wdec(u1), acc);
    }
    if (j < e) {
        unsigned int u0 = partC[j];
        unsigned int v0 = *(const unsigned int*)(hb8 + (u0 & 0x1FFFF) * NCLS + d * 4);
        fp8x4_fma(v0, wdec(u0), acc);
    }
#pragma unroll
    for (int i = 0; i < 4; i++) {
        acc[i] += __shfl_xor(acc[i], 8);
        acc[i] += __shfl_xor(acc[i], 16);
        acc[i] += __shfl_xor(acc[i], 32);
    }
    float dn = dinv[n];
    float4 hv = *(const float4*)(ha + (long)n * NCLS + d * 4);
    float v0 = dn * acc[0] + hv.x;
    float v1 = dn * acc[1] + hv.y;
    float v2 = dn * acc[2] + hv.z;
    float v3 = dn * acc[3] + hv.w;
    float m = fmaxf(fmaxf(v0, v1), fmaxf(v2, v3));
    m = fmaxf(m, __shfl_xor(m, 1));
    m = fmaxf(m, __shfl_xor(m, 2));
    m = fmaxf(m, __shfl_xor(m, 4));
    float sum = __expf(v0 - m) + __expf(v1 - m) + __expf(v2 - m) + __expf(v3 - m);
    sum += __shfl_xor(sum, 1);
    sum += __shfl_xor(sum, 2);
    sum += __shfl_xor(sum, 4);
    float ls = logf(sum);
    if (p == 0) {
        float4 o; o.x = v0 - m - ls; o.y = v1 - m - ls;
        o.z = v2 - m - ls; o.w = v3 - m - ls;
        *(float4*)(out + (long)n * NCLS + d * 4) = o;
    }
}

extern "C" void kernel_launch(void* const* d_in, const int* in_sizes, int n_in,
                              void* d_out, int out_size, void* d_ws, size_t ws_size,
                              hipStream_t stream) {
    const float* x    = (const float*)d_in[0];
    const int*   ei   = (const int*)d_in[1];
    const float* ew   = (const float*)d_in[2];
    const float* W1_0 = (const float*)d_in[3];
    const float* W1_1 = (const float*)d_in[4];
    const float* b1   = (const float*)d_in[5];
    const float* W2_0 = (const float*)d_in[6];
    const float* W2_1 = (const float*)d_in[7];
    const float* b2   = (const float*)d_in[8];
    float* out = (float*)d_out;

    const int* row = ei;
    const int* col = ei + NE;

    char* ws = (char*)d_ws;
    int2*  partS     = (int2*)ws;                 ws += sizeof(int2) * (long)NBKT * CAP;
    unsigned int* partC = (unsigned int*)ws;      ws += sizeof(int) * NE;
    int*   bucketCursor = (int*)ws;               ws += sizeof(int) * NBKT;
    int*   bucketStart  = (int*)ws;               ws += sizeof(int) * NBKT;
    int*   rowptr    = (int*)ws;                  ws += sizeof(int) * (NN + 4);
    float* dinv      = (float*)ws;                ws += sizeof(float) * NN;
    float* xa        = (float*)ws;                ws += sizeof(float) * NN * HID;
    float* agg1      = (float*)ws;                ws += sizeof(float) * NN * HID;
    float* ha        = (float*)ws;                ws += sizeof(float) * NN * NCLS;
    unsigned char* xb8 = (unsigned char*)ws;      ws += sizeof(char) * NN * HID;
    unsigned char* hb8 = (unsigned char*)ws;      ws += sizeof(char) * NN * NCLS;

    k_zero_cur<<<(NBKT + 255) / 256, 256, 0, stream>>>(bucketCursor);
    k_partition<<<GP, 256, 0, stream>>>(row, col, ew, bucketCursor, partS);
    k_scan_buckets<<<1, 64, 0, stream>>>(bucketCursor, bucketStart);
    k_bucket_sort<<<NBKT, 256, 0, stream>>>(partS, bucketCursor, bucketStart,
                                            partC, rowptr, dinv);
    k_proj1<<<(NTILE * 64 + 255) / 256, 256, 0, stream>>>(x, W1_0, W1_1, b1, dinv, xa, xb8);
    {
        long th = (long)NN * 64;
        k_gather1<<<(int)((th + 255) / 256), 256, 0, stream>>>(rowptr, partC, dinv, xb8, agg1);
    }
    k_proj2<<<(NN + 255) / 256, 256, 0, stream>>>(xa, agg1, W2_0, W2_1, b2, dinv, ha, hb8);
    {
        long th = (long)NN * 64;
        k_gather2_lsm<<<(int)((th + 255) / 256), 256, 0, stream>>>(rowptr, partC, dinv, ha, hb8, out);
    }
}